// Round 2
// baseline (223.718 us; speedup 1.0000x reference)
//
#include <hip/hip_runtime.h>
#include <math.h>

#define BB   16
#define TT   1026
#define LEN  1024
#define NTOT (BB*LEN)        // 16384
#define NX   (BB*TT*64)      // 1050624 floats in x

typedef __attribute__((ext_vector_type(8))) short bf16x8;
typedef __attribute__((ext_vector_type(4))) float f32x4;

// ---- ws byte offsets (unchanged layout) ----
#define OXH   ((size_t)0)                     // XH: NX shorts
#define OXL   (OXH + (size_t)NX*2)            // XL: NX shorts
#define OW1H  (OXL + (size_t)NX*2)            // 64 l * 8192 shorts
#define OW1L  (OW1H + (size_t)64*8192*2)
#define OW2H  (OW1L + (size_t)64*8192*2)      // 64 l * 4096 shorts
#define OW2L  (OW2H + (size_t)64*4096*2)
#define OWLH  (OW2L + (size_t)64*4096*2)      // w1_last hi (pi-slot order): 64 l * 64 shorts
#define OWLL  (OWLH + (size_t)64*64*2)
#define ORSV  (OWLL + (size_t)64*64*2)        // f32 [64*64]
#define OPD   (ORSV + (size_t)64*64*4)        // f32 [64][16384]

__device__ __forceinline__ unsigned int rne16(unsigned int u) {
    return (u + 0x7FFFu + ((u >> 16) & 1u)) >> 16;
}
__device__ __forceinline__ void split2(float v, short* h, short* s) {
    unsigned int u  = __float_as_uint(v);
    unsigned int hi = rne16(u);
    float lof = v - __uint_as_float(hi << 16);
    *h = (short)hi;
    *s = (short)rne16(__float_as_uint(lof));
}
// masked frag: half = (a positive ? w : 0). Exact: mask in {0,1}.
__device__ __forceinline__ bf16x8 maskand(bf16x8 a, bf16x8 w) {
    union { bf16x8 v; unsigned int u[4]; } A, W, M;
    A.v = a; W.v = w;
    #pragma unroll
    for (int j = 0; j < 4; ++j) {
        unsigned int t = (~A.u[j]) & 0x80008000u;   // sign==0 (positive) halves
        M.u[j] = ((t >> 15) * 0xFFFFu) & W.u[j];
    }
    return M.v;
}

// ---- fused prep ----
// blocks [0,1026):   x -> XH/XL                         (unchanged)
// blocks [1026,1410): weight frags; W1 canonical k-order (unchanged),
//                     W2 in pi k-order: h = kc2*32 + (j>>2)*16 + q*4 + (j&3)
// blocks [1410,1474): w1_last split in pi slot order + RSV
__global__ __launch_bounds__(256)
void prep_all(const float* __restrict__ x, const float* __restrict__ W1,
              const float* __restrict__ W2,
              short* __restrict__ XH, short* __restrict__ XL,
              short* __restrict__ W1H, short* __restrict__ W1L,
              short* __restrict__ W2H, short* __restrict__ W2L,
              short* __restrict__ WLH, short* __restrict__ WLL,
              float* __restrict__ RSV)
{
    const int b = blockIdx.x, tid = threadIdx.x;
    if (b < 1026) {
        int i = (b * 256 + tid) * 4;
        float4 v = *(const float4*)(x + i);
        float vv[4] = {v.x, v.y, v.z, v.w};
        short hh[4], ll[4];
        #pragma unroll
        for (int j = 0; j < 4; ++j) split2(vv[j], &hh[j], &ll[j]);
        *(short4*)&XH[i] = make_short4(hh[0], hh[1], hh[2], hh[3]);
        *(short4*)&XL[i] = make_short4(ll[0], ll[1], ll[2], ll[3]);
    } else if (b < 1410) {
        int e = (b - 1026) * 256 + tid;          // 0..98303
        int l = e / 1536, r = e - l * 1536;
        if (r < 1024) {                           // W1 frag elem (canonical k-order)
            int fid = r >> 6, lane = r & 63;
            int fk = fid >> 2, nt = fid & 3;
            int h  = nt * 16 + (lane & 15);
            int f0 = fk * 32 + (lane >> 4) * 8;
            const float* src = W1 + (size_t)l * 8256 + h * 129 + f0;
            size_t o = (size_t)l * 8192 + (size_t)r * 8;
            #pragma unroll
            for (int j = 0; j < 8; ++j) {
                short h_, l_; split2(src[j], &h_, &l_);
                W1H[o + j] = h_; W1L[o + j] = l_;
            }
        } else {                                  // W2 frag elem in pi k-order
            int r2 = r - 1024;
            int fid = r2 >> 6, lane = r2 & 63;
            int kc2 = fid >> 2, nt = fid & 3;
            int g  = nt * 16 + (lane & 15);
            int qq = lane >> 4;
            const float* src = W2 + (size_t)l * 4096 + g * 64 + kc2 * 32 + qq * 4;
            size_t o = (size_t)l * 4096 + (size_t)r2 * 8;
            #pragma unroll
            for (int j = 0; j < 8; ++j) {
                int hoff = ((j >> 2) << 4) + (j & 3);   // jj*16 + r
                short h_, l_; split2(src[hoff], &h_, &l_);
                W2H[o + j] = h_; W2L[o + j] = l_;
            }
        }
    } else {
        const int l = b - 1410;
        if (tid < 64) {
            int h = tid;
            float wl = W1[(size_t)l * 8256 + h * 129 + 128];
            short h_, l_; split2(wl, &h_, &l_);
            // slot s such that pi(s) = h
            int s = (h >> 5) * 32 + ((h >> 2) & 3) * 8 + ((h >> 4) & 1) * 4 + (h & 3);
            WLH[l * 64 + s] = h_; WLL[l * 64 + s] = l_;
            float sacc = 0.f;
            #pragma unroll 4
            for (int hh = 0; hh < 64; ++hh)
                sacc += W2[(size_t)l * 4096 + tid * 64 + hh] * W1[(size_t)l * 8256 + hh * 129 + 128];
            RSV[l * 64 + tid] = sacc;
        }
    }
}

// logdet[n] = sum_l log|PD[l][n]|
__global__ __launch_bounds__(256)
void finish_logdet(const float* __restrict__ PD, float* __restrict__ logdet) {
    int i = blockIdx.x * 256 + threadIdx.x;
    float acc = 0.f;
    #pragma unroll 8
    for (int l = 0; l < 64; ++l)
        acc += __logf(fabsf(PD[(size_t)l * NTOT + i]));
    logdet[i] = acc;
}

// LDS-free main kernel: operand-swapped MFMAs keep the whole pipeline lane-local.
// Stage 1: z1^T = mfma(W1frag, Xfrag)  -> lane holds a1[n=c16][h=nt*16+q*4+r]
// Stage 2 (k in pi order, baked into W2/WL prep): B-frag dwords == the packed
//          (hi,lo) pair dwords produced by finalize. Zero shuffles, zero LDS.
// Epilogue: z2^T -> per-lane partial over g, 2x shfl_xor, writer lane q==mt.
__global__ __launch_bounds__(256, 2)
void np_main(const float* __restrict__ x,  const float* __restrict__ W1,
             const float* __restrict__ b1, const float* __restrict__ b2,
             const float* __restrict__ W3, const float* __restrict__ b3,
             const short* __restrict__ XH, const short* __restrict__ XL,
             const short* __restrict__ W1H, const short* __restrict__ W1L,
             const short* __restrict__ W2H, const short* __restrict__ W2L,
             const short* __restrict__ WLH, const short* __restrict__ WLL,
             const float* __restrict__ RSV, float* __restrict__ PD,
             float* __restrict__ out)
{
    const int l = blockIdx.x, tid = threadIdx.x;
    const int nb = blockIdx.y * 256;
    const int bb = nb >> 10, t0 = nb & 1023;
    const int lane = tid & 63, wid = tid >> 6;
    const int q = lane >> 4, c16 = lane & 15;
    const int wrow = wid * 64;
    const size_t xrow0 = (size_t)(bb * TT + t0);

    // x_t loads issued early (hidden under stage-1 MFMA)
    float xt[4];
    #pragma unroll
    for (int mt = 0; mt < 4; ++mt)
        xt[mt] = x[(xrow0 + wrow + mt * 16 + c16 + 2) * 64 + l];

    // ---- stage 1: zT[nt][mt] = W1' @ x_lags^T, 3-pass hi/lo split ----
    f32x4 zT[4][4];
    #pragma unroll
    for (int nt = 0; nt < 4; ++nt)
        #pragma unroll
        for (int mt = 0; mt < 4; ++mt) zT[nt][mt] = (f32x4){0.f, 0.f, 0.f, 0.f};

    const short* w1hb = W1H + (size_t)l * 8192;
    const short* w1lb = W1L + (size_t)l * 8192;
    #pragma unroll
    for (int fk = 0; fk < 4; ++fk) {
        const int colx = (fk & 1) * 32 + q * 8;
        const int rofs = fk >> 1;
        bf16x8 xh[4], xl[4], wh[4], wl[4];
        #pragma unroll
        for (int mt = 0; mt < 4; ++mt) {
            size_t xo = (xrow0 + wrow + mt * 16 + c16 + rofs) * 64 + colx;
            xh[mt] = *(const bf16x8*)(XH + xo);
            xl[mt] = *(const bf16x8*)(XL + xo);
        }
        #pragma unroll
        for (int nt = 0; nt < 4; ++nt) {
            size_t wo = (size_t)((fk * 4 + nt) * 64 + lane) * 8;
            wh[nt] = *(const bf16x8*)(w1hb + wo);
            wl[nt] = *(const bf16x8*)(w1lb + wo);
        }
        #pragma unroll
        for (int nt = 0; nt < 4; ++nt)
            #pragma unroll
            for (int mt = 0; mt < 4; ++mt) {
                zT[nt][mt] = __builtin_amdgcn_mfma_f32_16x16x32_bf16(wh[nt], xh[mt], zT[nt][mt], 0, 0, 0);
                zT[nt][mt] = __builtin_amdgcn_mfma_f32_16x16x32_bf16(wh[nt], xl[mt], zT[nt][mt], 0, 0, 0);
                zT[nt][mt] = __builtin_amdgcn_mfma_f32_16x16x32_bf16(wl[nt], xh[mt], zT[nt][mt], 0, 0, 0);
            }
    }

    // ---- finalize: a1 = leaky(zT + xt*w1_last + b1); pack frag dwords ----
    // pkh[nt][mt][p] = [bf16hi(r=2p) | bf16hi(r=2p+1)<<16], pkl = lo parts.
    // split2 (proven bit-ops) — no inline-asm cvt.
    unsigned pkh[4][4][2], pkl[4][4][2];
    #pragma unroll
    for (int nt = 0; nt < 4; ++nt) {
        float4 b1c = *(const float4*)(b1 + l * 64 + nt * 16 + q * 4);
        float b1a[4] = {b1c.x, b1c.y, b1c.z, b1c.w};
        float w1c[4];
        #pragma unroll
        for (int r = 0; r < 4; ++r)
            w1c[r] = W1[(size_t)(l * 64 + nt * 16 + q * 4 + r) * 129 + 128];
        #pragma unroll
        for (int mt = 0; mt < 4; ++mt) {
            #pragma unroll
            for (int p = 0; p < 2; ++p) {
                float v0 = zT[nt][mt][2*p]   + xt[mt] * w1c[2*p]   + b1a[2*p];
                float v1 = zT[nt][mt][2*p+1] + xt[mt] * w1c[2*p+1] + b1a[2*p+1];
                float a0 = fmaxf(v0, 0.01f * v0);
                float a1v = fmaxf(v1, 0.01f * v1);
                short h0, s0, h1, s1;
                split2(a0,  &h0, &s0);
                split2(a1v, &h1, &s1);
                pkh[nt][mt][p] = (unsigned)(unsigned short)h0 | ((unsigned)(unsigned short)h1 << 16);
                pkl[nt][mt][p] = (unsigned)(unsigned short)s0 | ((unsigned)(unsigned short)s1 << 16);
            }
        }
    }

    // ---- stage 2 + epilogue, mt-outer, all in registers ----
    union U { bf16x8 v; unsigned u[4]; };
    U wlph[2], wlpl[2];
    #pragma unroll
    for (int kc2 = 0; kc2 < 2; ++kc2) {
        wlph[kc2].v = *(const bf16x8*)&WLH[l * 64 + kc2 * 32 + q * 8];
        wlpl[kc2].v = *(const bf16x8*)&WLL[l * 64 + kc2 * 32 + q * 8];
    }
    const short* w2hb = W2H + (size_t)l * 4096;
    const short* w2lb = W2L + (size_t)l * 4096;
    const float b3l = b3[l];
    float po_keep = 0.f, pd_keep = 0.f;

    #pragma unroll
    for (int mt = 0; mt < 4; ++mt) {
        f32x4 za[4], zm[4];
        #pragma unroll
        for (int gt = 0; gt < 4; ++gt) {
            za[gt] = (f32x4){0.f, 0.f, 0.f, 0.f};
            zm[gt] = (f32x4){0.f, 0.f, 0.f, 0.f};
        }
        #pragma unroll
        for (int kc2 = 0; kc2 < 2; ++kc2) {
            U ah, al;
            ah.u[0] = pkh[2*kc2  ][mt][0]; ah.u[1] = pkh[2*kc2  ][mt][1];
            ah.u[2] = pkh[2*kc2+1][mt][0]; ah.u[3] = pkh[2*kc2+1][mt][1];
            al.u[0] = pkl[2*kc2  ][mt][0]; al.u[1] = pkl[2*kc2  ][mt][1];
            al.u[2] = pkl[2*kc2+1][mt][0]; al.u[3] = pkl[2*kc2+1][mt][1];
            bf16x8 mh = maskand(ah.v, wlph[kc2].v);
            bf16x8 ml = maskand(ah.v, wlpl[kc2].v);
            #pragma unroll
            for (int gt = 0; gt < 4; ++gt) {
                size_t wo = (size_t)((kc2 * 4 + gt) * 64 + lane) * 8;
                bf16x8 w2h = *(const bf16x8*)(w2hb + wo);
                bf16x8 w2l = *(const bf16x8*)(w2lb + wo);
                za[gt] = __builtin_amdgcn_mfma_f32_16x16x32_bf16(w2h, ah.v, za[gt], 0, 0, 0);
                za[gt] = __builtin_amdgcn_mfma_f32_16x16x32_bf16(w2h, al.v, za[gt], 0, 0, 0);
                za[gt] = __builtin_amdgcn_mfma_f32_16x16x32_bf16(w2l, ah.v, za[gt], 0, 0, 0);
                zm[gt] = __builtin_amdgcn_mfma_f32_16x16x32_bf16(w2h, mh,   zm[gt], 0, 0, 0);
                zm[gt] = __builtin_amdgcn_mfma_f32_16x16x32_bf16(w2l, mh,   zm[gt], 0, 0, 0);
                zm[gt] = __builtin_amdgcn_mfma_f32_16x16x32_bf16(w2h, ml,   zm[gt], 0, 0, 0);
            }
        }
        // epilogue for this n-tile: g = gt*16 + q*4 + r is lane-local
        float po = 0.f, pd = 0.f;
        #pragma unroll
        for (int gt = 0; gt < 4; ++gt) {
            float4 b2c = *(const float4*)(b2 + l * 64 + gt * 16 + q * 4);
            float4 w3c = *(const float4*)(W3 + l * 64 + gt * 16 + q * 4);
            float4 rc  = *(const float4*)(RSV + l * 64 + gt * 16 + q * 4);
            float b2a[4] = {b2c.x, b2c.y, b2c.z, b2c.w};
            float w3a[4] = {w3c.x, w3c.y, w3c.z, w3c.w};
            float rca[4] = {rc.x,  rc.y,  rc.z,  rc.w};
            #pragma unroll
            for (int r = 0; r < 4; ++r) {
                float zv = za[gt][r] + b2a[r];
                float a2 = fmaxf(zv, 0.01f * zv);
                float zt = 0.99f * zm[gt][r] + 0.01f * rca[r];
                po += a2 * w3a[r];
                pd += (zv > 0.f ? w3a[r] : 0.01f * w3a[r]) * zt;
            }
        }
        po += __shfl_xor(po, 16);
        po += __shfl_xor(po, 32);
        pd += __shfl_xor(pd, 16);
        pd += __shfl_xor(pd, 32);
        if (q == mt) { po_keep = po; pd_keep = pd; }
    }

    const int n = nb + wrow + lane;         // lane == mt*16+c16 for mt==q
    out[(size_t)n * 64 + l] = po_keep + b3l;
    PD[(size_t)l * NTOT + n] = pd_keep;     // coalesced
}

extern "C" void kernel_launch(void* const* d_in, const int* in_sizes, int n_in,
                              void* d_out, int out_size, void* d_ws, size_t ws_size,
                              hipStream_t stream) {
    const float* x  = (const float*)d_in[0];
    const float* W1 = (const float*)d_in[1];
    const float* b1 = (const float*)d_in[2];
    const float* W2 = (const float*)d_in[3];
    const float* b2 = (const float*)d_in[4];
    const float* W3 = (const float*)d_in[5];
    const float* b3 = (const float*)d_in[6];
    float* out = (float*)d_out;
    char* ws = (char*)d_ws;

    short* XH   = (short*)(ws + OXH);
    short* XL   = (short*)(ws + OXL);
    short* W1Hp = (short*)(ws + OW1H);
    short* W1Lp = (short*)(ws + OW1L);
    short* W2Hp = (short*)(ws + OW2H);
    short* W2Lp = (short*)(ws + OW2L);
    short* WLHp = (short*)(ws + OWLH);
    short* WLLp = (short*)(ws + OWLL);
    float* RSVp = (float*)(ws + ORSV);
    float* PDp  = (float*)(ws + OPD);

    hipLaunchKernelGGL(prep_all, dim3(1026 + 384 + 64), dim3(256), 0, stream,
                       x, W1, W2, XH, XL, W1Hp, W1Lp, W2Hp, W2Lp, WLHp, WLLp, RSVp);
    dim3 grid(64 /*l*/, NTOT / 256 /*n tiles of 256*/);
    hipLaunchKernelGGL(np_main, grid, dim3(256), 0, stream,
                       x, W1, b1, b2, W3, b3,
                       XH, XL, W1Hp, W1Lp, W2Hp, W2Lp, WLHp, WLLp, RSVp, PDp, out);
    hipLaunchKernelGGL(finish_logdet, dim3(NTOT / 256), dim3(256), 0, stream,
                       PDp, out + (size_t)NTOT * 64);
}